// Round 4
// baseline (2971.422 us; speedup 1.0000x reference)
//
#include <hip/hip_runtime.h>
#include <math.h>

#define MDIM   4096
#define NSTEPS 199
#define NBLK   256     // one block per CU
#define NTHR   1024    // 16 waves
#define B1C    0.9f
#define B2C    0.999f
#define EPSC   1e-8f

typedef unsigned long long u64;

// Tagged u element: high 32 = step tag, low 32 = float bits. One 8-byte
// relaxed agent-scope atomic carries data AND readiness (self-validating).
__device__ __forceinline__ u64 pack_uv(float v, unsigned t) {
    return ((u64)t << 32) | (u64)__float_as_uint(v);
}
__device__ __forceinline__ float    unpack_v(u64 p) { return __uint_as_float((unsigned)p); }
__device__ __forceinline__ unsigned unpack_t(u64 p) { return (unsigned)(p >> 32); }

// ---------------------------------------------------------------------------
// Init: u0 tagged 0 with value 1-mean. u1 MUST get a sentinel tag: stale u1
// tags from a previous graph-replay launch end at 197, which would alias
// step 198's expected tag and silently feed stale data.
// ---------------------------------------------------------------------------
__global__ void init_state(const float* __restrict__ mean,
                           u64* __restrict__ u0, u64* __restrict__ u1) {
    int i = blockIdx.x * blockDim.x + threadIdx.x;
    if (i < MDIM) {
        u0[i] = pack_uv(1.0f - mean[i], 0u);
        u1[i] = pack_uv(0.0f, 0xFFFFFFFFu);
    }
}

// ---------------------------------------------------------------------------
// Persistent cooperative kernel — NO flags, NO aggregator, NO go word.
// Wave w of block b holds Q[16b..16b+15][256w+4l..+3] in 64 regs/lane,
// built in the prologue directly from va (0.5*(va[r][c]+va[c][r]),
// bit-identical to the old prep_qs). Per step:
//   - each lane loads its 4 tagged u64 elements; retries ONLY the elements
//     whose tag != t-1 (miss set shrinks to late producers' lines within
//     1-2 RTs; s_sleep(8) backoff from round 3 caps congestion),
//   - __syncthreads = block-wide vote: all 4096 elements of u_{t-1} seen
//     => every block published u_{t-1} => every block read u_{t-2}
//     => WAR-safe to overwrite the u_{t-2} buffer. Sync chain is now
//     2 coherence legs (store visible + retry detect) instead of 5.
//   - dot from registers, 30-shuffle fold + 16x17 pr matrix (validated),
//   - Adam in registers, publish ONE tagged 8B store. 2 barriers/step.
// ---------------------------------------------------------------------------
__global__ __launch_bounds__(NTHR) void adam_persist(
        const float* __restrict__ va,
        u64* u0, u64* u1,
        const float* __restrict__ mean,
        float* __restrict__ w_out) {
    __shared__ float pr[2][16][17];   // [buf][wave][local row], +1 pad

    const int tid  = threadIdx.x;
    const int bid  = blockIdx.x;
    const int wave = tid >> 6;
    const int lane = tid & 63;
    const int row  = bid * 16 + wave;
    const int col0 = wave * 256 + lane * 4;    // this lane's 4-element segment

    // ---- one-time: Q fragment -> registers, straight from va ----
    // qreg[r] = 0.5*(va[16b+r][col0..+3] + va[col0..+3][16b+r])
    float4 qreg[16];
#pragma unroll
    for (int r = 0; r < 16; ++r)
        qreg[r] = *(const float4*)(va + (size_t)(bid * 16 + r) * MDIM + col0);

    // transpose part: col c's line va[col0+c][16b..16b+15] = 64B, one read
    // reused across all 16 local rows.
#define XPOSE(c, comp)                                                        \
    {                                                                         \
        const float* vp = va + (size_t)(col0 + (c)) * MDIM + bid * 16;        \
        float4 a0 = *(const float4*)(vp + 0);                                 \
        float4 a1 = *(const float4*)(vp + 4);                                 \
        float4 a2 = *(const float4*)(vp + 8);                                 \
        float4 a3 = *(const float4*)(vp + 12);                                \
        float tv[16] = {a0.x, a0.y, a0.z, a0.w, a1.x, a1.y, a1.z, a1.w,       \
                        a2.x, a2.y, a2.z, a2.w, a3.x, a3.y, a3.z, a3.w};      \
        _Pragma("unroll")                                                     \
        for (int r = 0; r < 16; ++r)                                          \
            qreg[r].comp = 0.5f * (qreg[r].comp + tv[r]);                     \
    }
    XPOSE(0, x) XPOSE(1, y) XPOSE(2, z) XPOSE(3, w)
#undef XPOSE

    float m = 0.0f, v = 0.0f, b1p = 1.0f, b2p = 1.0f;
    const float mrow = mean[row];
    float ucur = 1.0f - mrow;                  // u[row] lives in registers

    for (int t = 1; t <= NSTEPS; ++t) {
        u64* uin  = (t & 1) ? u0 : u1;         // t=1 reads u0 (tag 0)
        u64* uout = (t & 1) ? u1 : u0;
        const unsigned tg = (unsigned)(t - 1);
        const int b = t & 1;

        // ---- fetch with miss-only retry; loop self-paces at load RT ----
        u64 e0, e1, e2, e3;
        unsigned pending = 0xFu;
        int round = 0;
        for (;;) {
            if (pending & 1u) e0 = __hip_atomic_load(uin + col0 + 0, __ATOMIC_RELAXED, __HIP_MEMORY_SCOPE_AGENT);
            if (pending & 2u) e1 = __hip_atomic_load(uin + col0 + 1, __ATOMIC_RELAXED, __HIP_MEMORY_SCOPE_AGENT);
            if (pending & 4u) e2 = __hip_atomic_load(uin + col0 + 2, __ATOMIC_RELAXED, __HIP_MEMORY_SCOPE_AGENT);
            if (pending & 8u) e3 = __hip_atomic_load(uin + col0 + 3, __ATOMIC_RELAXED, __HIP_MEMORY_SCOPE_AGENT);
            if ((pending & 1u) && unpack_t(e0) == tg) pending &= ~1u;
            if ((pending & 2u) && unpack_t(e1) == tg) pending &= ~2u;
            if ((pending & 4u) && unpack_t(e2) == tg) pending &= ~4u;
            if ((pending & 8u) && unpack_t(e3) == tg) pending &= ~8u;
            if (!pending) break;
            if (++round > 2) __builtin_amdgcn_s_sleep(8);  // congestion guard
            if (round > (1 << 16)) break;      // fail visibly, never hang
        }
        const float uv0 = unpack_v(e0), uv1 = unpack_v(e1);
        const float uv2 = unpack_v(e2), uv3 = unpack_v(e3);

        // Block-wide vote: all lanes validated their elements -> the whole
        // u_{t-1} is published -> WAR-safe to write uout below. Also orders
        // pr[b] reuse (2 barriers/step separate t's writes from t-2's reads).
        __syncthreads();

        // ---- 16 row-partials over this lane's 4 columns ----
        float acc[16];
#pragma unroll
        for (int r = 0; r < 16; ++r) {
            float4 q = qreg[r];
            acc[r] = q.x * uv0 + q.y * uv1 + q.z * uv2 + q.w * uv3;
        }

        // ---- fold 16 values x 64 lanes -> 1 value/lane (30 shuffles) ----
#pragma unroll
        for (int stage = 0; stage < 4; ++stage) {
            const int mask = 32 >> stage;
            const int half = 8 >> stage;
            const bool hi = (lane & mask) != 0;
#pragma unroll
            for (int i = 0; i < half; ++i) {
                float plo = __shfl_xor(acc[i],        mask);
                float phi = __shfl_xor(acc[i + half], mask);
                acc[i] = hi ? (acc[i + half] + phi) : (acc[i] + plo);
            }
        }
        float acc0 = acc[0];
        acc0 += __shfl_xor(acc0, 1);   // finish sum within the quad
        acc0 += __shfl_xor(acc0, 2);

        if ((lane & 3) == 0) pr[b][wave][lane >> 2] = acc0;
        __syncthreads();               // pr matrix ready

        // ---- cross-wave fold: wave w reduces local row w; Adam in regs ----
        float unew = ucur;
        if (lane < 16) {
            float p = pr[b][lane][wave];
            p += __shfl_xor(p, 1);
            p += __shfl_xor(p, 2);
            p += __shfl_xor(p, 4);
            p += __shfl_xor(p, 8);
            const float g = p;

            b1p *= B1C;
            b2p *= B2C;
            m = B1C * m + (1.0f - B1C) * g;
            v = B2C * v + (1.0f - B2C) * g * g;
            const float denom = sqrtf(v) / sqrtf(1.0f - b2p) + EPSC;
            unew = ucur - (0.1f / (1.0f - b1p)) * m / denom;
            ucur = unew;
        }

        // ---- publish: ONE tagged 8B store; tag+value travel together ----
        if (t < NSTEPS) {              // nobody consumes u_199 from memory
            if (lane == 0)
                __hip_atomic_store(uout + row, pack_uv(unew, (unsigned)t),
                                   __ATOMIC_RELAXED, __HIP_MEMORY_SCOPE_AGENT);
        }
    }

    if (lane == 0) w_out[row] = ucur + mrow;
}

extern "C" void kernel_launch(void* const* d_in, const int* in_sizes, int n_in,
                              void* d_out, int out_size, void* d_ws, size_t ws_size,
                              hipStream_t stream) {
    const float* mean = (const float*)d_in[0];   // (4096,)
    const float* va   = (const float*)d_in[1];   // (4096,4096)
    float* w_out = (float*)d_out;                // (4096,)

    u64* u0 = (u64*)d_ws;                        // 32 KB tagged
    u64* u1 = u0 + MDIM;                         // 32 KB tagged

    init_state<<<(MDIM + 255) / 256, 256, 0, stream>>>(mean, u0, u1);

    void* args[] = { (void*)&va, (void*)&u0, (void*)&u1,
                     (void*)&mean, (void*)&w_out };
    hipLaunchCooperativeKernel((const void*)adam_persist,
                               dim3(NBLK), dim3(NTHR), args, 0, stream);
}

// Round 5
// 1385.417 us; speedup vs baseline: 2.1448x; 2.1448x over previous
//
#include <hip/hip_runtime.h>
#include <math.h>

#define MDIM   4096
#define NSTEPS 199
#define NBLK   256     // one block per CU
#define NTHR   1024    // 16 waves
#define B1C    0.9f
#define B2C    0.999f
#define EPSC   1e-8f

typedef unsigned long long u64;

// ---------------------------------------------------------------------------
// Prep: Qs[i][j] = 0.5*(va[i][j] + va[j][i]), LDS-tiled transpose (validated).
// ---------------------------------------------------------------------------
__global__ void prep_qs(const float* __restrict__ va, float* __restrict__ Qs) {
    __shared__ float tile[32][33];
    const int j0 = blockIdx.x * 32;
    const int i0 = blockIdx.y * 32;
    const int tx = threadIdx.x, ty = threadIdx.y;

    for (int k = 0; k < 32; k += 8)
        tile[ty + k][tx] = va[(size_t)(j0 + ty + k) * MDIM + i0 + tx];
    __syncthreads();
    for (int k = 0; k < 32; k += 8) {
        int i = i0 + ty + k;
        float a = va[(size_t)i * MDIM + j0 + tx];
        float b = tile[tx][ty + k];          // va[j][i]
        Qs[(size_t)i * MDIM + j0 + tx] = 0.5f * (a + b);
    }
}

// ---------------------------------------------------------------------------
// Init: u0 = 1 - mean; counters zeroed except cnt[0]=NBLK (u_0 is ready by
// stream order + kernel-end cache flush of init_state).
// ---------------------------------------------------------------------------
__global__ void init_state(const float* __restrict__ mean,
                           float* __restrict__ u0,
                           int* __restrict__ cnt, int ncnt) {
    int i = blockIdx.x * blockDim.x + threadIdx.x;
    if (i < MDIM) u0[i] = 1.0f - mean[i];
    if (i < ncnt) cnt[i] = (i == 0) ? NBLK : 0;
}

// ---------------------------------------------------------------------------
// Persistent cooperative kernel — counter barrier (3 coherence legs).
// Wave w of block b holds Q[16b..16b+15][256w+4l..+3] in 64 regs/lane.
// Per step:
//   - tid0 polls cnt[t-1]==NBLK: ONE line, ONE poller per block (the
//     congestion-free pattern validated by round 3's go-poll). cnt[t-1]==256
//     proves every block drained its u_{t-1} stores (B2 idiom: s_waitcnt
//     vmcnt(0) before s_barrier in every wave) AND finished reading u_{t-2}
//     (data dependence) -> RAW and WAR both safe.
//   - load u segment (2x8B agent atomics, 16 B/lane = minimal traffic),
//   - dot from registers, 30-shuffle fold + 16x17 pr matrix (validated),
//   - Adam in registers; publish u[row]; B2 drains; tid0 atomicAdd(cnt+t,1).
// Chain after last producer: add visible (1 leg) -> detect (~1.5) -> u load
// (1) — vs round 3's 5 legs (flag -> agg detect -> go -> detect -> load).
// ---------------------------------------------------------------------------
__global__ __launch_bounds__(NTHR) void adam_persist(
        const float* __restrict__ Qs,
        float* u0, float* u1,
        const float* __restrict__ mean,
        float* __restrict__ w_out,
        int* __restrict__ cnt) {
    __shared__ float pr[2][16][17];   // [buf][wave][local row], +1 pad

    const int tid  = threadIdx.x;
    const int bid  = blockIdx.x;
    const int wave = tid >> 6;
    const int lane = tid & 63;
    const int row  = bid * 16 + wave;
    const int col0 = wave * 256 + lane * 4;    // this lane's 4-element segment

    // ---- one-time: Q fragment -> registers (64 regs/lane) ----
    float4 qreg[16];
#pragma unroll
    for (int r = 0; r < 16; ++r)
        qreg[r] = *(const float4*)(Qs + (size_t)(bid * 16 + r) * MDIM + col0);

    float m = 0.0f, v = 0.0f, b1p = 1.0f, b2p = 1.0f;
    const float mrow = mean[row];
    float ucur = 1.0f - mrow;                  // u[row] lives in registers

    for (int t = 1; t <= NSTEPS; ++t) {
        const float* uin = (t & 1) ? u0 : u1;  // t=1 reads u0
        float*      uout = (t & 1) ? u1 : u0;  // u_t lands in buffer t&1
        const int b = t & 1;

        // ---- counter barrier: wait for u_{t-1} fully published ----
        if (tid == 0) {
            int spin = 0;
            while (__hip_atomic_load(cnt + (t - 1), __ATOMIC_RELAXED,
                                     __HIP_MEMORY_SCOPE_AGENT) != NBLK) {
                if (++spin > (1 << 24)) break;   // fail visibly, never hang
            }
        }
        __syncthreads();               // B_go: u_{t-1} visible to all lanes

        // ---- load u segment (2x8B agent atomics bypass stale L2) ----
        u64 d0 = __hip_atomic_load((const u64*)(uin + col0),     __ATOMIC_RELAXED, __HIP_MEMORY_SCOPE_AGENT);
        u64 d1 = __hip_atomic_load((const u64*)(uin + col0 + 2), __ATOMIC_RELAXED, __HIP_MEMORY_SCOPE_AGENT);
        const float uv0 = __uint_as_float((unsigned)d0);
        const float uv1 = __uint_as_float((unsigned)(d0 >> 32));
        const float uv2 = __uint_as_float((unsigned)d1);
        const float uv3 = __uint_as_float((unsigned)(d1 >> 32));

        // ---- 16 row-partials over this lane's 4 columns ----
        float acc[16];
#pragma unroll
        for (int r = 0; r < 16; ++r) {
            float4 q = qreg[r];
            acc[r] = q.x * uv0 + q.y * uv1 + q.z * uv2 + q.w * uv3;
        }

        // ---- fold 16 values x 64 lanes -> 1 value/lane (30 shuffles) ----
#pragma unroll
        for (int stage = 0; stage < 4; ++stage) {
            const int mask = 32 >> stage;
            const int half = 8 >> stage;
            const bool hi = (lane & mask) != 0;
#pragma unroll
            for (int i = 0; i < half; ++i) {
                float plo = __shfl_xor(acc[i],        mask);
                float phi = __shfl_xor(acc[i + half], mask);
                acc[i] = hi ? (acc[i + half] + phi) : (acc[i] + plo);
            }
        }
        float acc0 = acc[0];
        acc0 += __shfl_xor(acc0, 1);   // finish sum within the quad
        acc0 += __shfl_xor(acc0, 2);

        if ((lane & 3) == 0) pr[b][wave][lane >> 2] = acc0;
        __syncthreads();               // B1: pr matrix ready

        // ---- cross-wave fold: wave w reduces local row w; Adam in regs ----
        float unew = ucur;
        if (lane < 16) {
            float p = pr[b][lane][wave];
            p += __shfl_xor(p, 1);
            p += __shfl_xor(p, 2);
            p += __shfl_xor(p, 4);
            p += __shfl_xor(p, 8);
            const float g = p;

            b1p *= B1C;
            b2p *= B2C;
            m = B1C * m + (1.0f - B1C) * g;
            v = B2C * v + (1.0f - B2C) * g * g;
            const float denom = sqrtf(v) / sqrtf(1.0f - b2p) + EPSC;
            unew = ucur - (0.1f / (1.0f - b1p)) * m / denom;
            ucur = unew;
        }

        if (t < NSTEPS) {              // nobody consumes u_199 from memory
            if (lane == 0)
                __hip_atomic_store(uout + row, unew, __ATOMIC_RELAXED,
                                   __HIP_MEMORY_SCOPE_AGENT);
            // B2: each wave's s_waitcnt vmcnt(0) before s_barrier drains its
            // u store -> after the barrier ALL 16 rows are agent-visible.
            __syncthreads();

            if (tid == 0)
                __hip_atomic_fetch_add(cnt + t, 1, __ATOMIC_RELAXED,
                                       __HIP_MEMORY_SCOPE_AGENT);
        }
    }

    if (lane == 0) w_out[row] = ucur + mrow;
}

extern "C" void kernel_launch(void* const* d_in, const int* in_sizes, int n_in,
                              void* d_out, int out_size, void* d_ws, size_t ws_size,
                              hipStream_t stream) {
    const float* mean = (const float*)d_in[0];   // (4096,)
    const float* va   = (const float*)d_in[1];   // (4096,4096)
    float* w_out = (float*)d_out;                // (4096,)

    float* ws = (float*)d_ws;
    float* Qs  = ws;                              // 64 MB
    float* u0  = ws + (size_t)MDIM * MDIM;        // 16 KB
    float* u1  = u0 + MDIM;                       // 16 KB
    int*   cnt = (int*)(u1 + MDIM);               // (NSTEPS+1) ints

    const int ncnt = NSTEPS + 1;

    prep_qs<<<dim3(MDIM / 32, MDIM / 32), dim3(32, 8), 0, stream>>>(va, Qs);
    init_state<<<(MDIM + 255) / 256, 256, 0, stream>>>(mean, u0, cnt, ncnt);

    void* args[] = { (void*)&Qs, (void*)&u0, (void*)&u1,
                     (void*)&mean, (void*)&w_out, (void*)&cnt };
    hipLaunchCooperativeKernel((const void*)adam_persist,
                               dim3(NBLK), dim3(NTHR), args, 0, stream);
}

// Round 6
// 1254.040 us; speedup vs baseline: 2.3695x; 1.1048x over previous
//
#include <hip/hip_runtime.h>
#include <math.h>

#define MDIM   4096
#define NSTEPS 199
#define NBLK   256     // one block per CU
#define NTHR   1024    // 16 waves
#define B1C    0.9f
#define B2C    0.999f
#define EPSC   1e-8f

typedef unsigned long long u64;

// ---------------------------------------------------------------------------
// Prep: Qs[i][j] = 0.5*(va[i][j] + va[j][i]), LDS-tiled transpose (validated).
// ---------------------------------------------------------------------------
__global__ void prep_qs(const float* __restrict__ va, float* __restrict__ Qs) {
    __shared__ float tile[32][33];
    const int j0 = blockIdx.x * 32;
    const int i0 = blockIdx.y * 32;
    const int tx = threadIdx.x, ty = threadIdx.y;

    for (int k = 0; k < 32; k += 8)
        tile[ty + k][tx] = va[(size_t)(j0 + ty + k) * MDIM + i0 + tx];
    __syncthreads();
    for (int k = 0; k < 32; k += 8) {
        int i = i0 + ty + k;
        float a = va[(size_t)i * MDIM + j0 + tx];
        float b = tile[tx][ty + k];          // va[j][i]
        Qs[(size_t)i * MDIM + j0 + tx] = 0.5f * (a + b);
    }
}

// ---------------------------------------------------------------------------
// Init: u0 = 1 - mean; flags slot 0 preset to 1 (u_0 ready by stream order),
// all later slots 0.
// ---------------------------------------------------------------------------
__global__ void init_state(const float* __restrict__ mean,
                           float* __restrict__ u0,
                           int* __restrict__ flags, int nflags) {
    int i = blockIdx.x * blockDim.x + threadIdx.x;
    if (i < MDIM)   u0[i] = 1.0f - mean[i];
    if (i < nflags) flags[i] = (i < NBLK) ? 1 : 0;
}

// ---------------------------------------------------------------------------
// Persistent cooperative kernel — FLAT flag barrier (shortest proven-safe
// chain): producer drain(B2) -> flag store -> every block's wave 0 polls all
// 256 flags itself -> B_go -> u load. Removes round 3's aggregator detect +
// go-store legs (~1.75 RT). Poll traffic: 1 wave/block, 1KB sweep over 8
// lines per round ~= 256 KB/round grid-wide (same per-line request rate as
// round 3's proven go-line poll; 16x under the measured congestion modes).
// Readiness writes stay contention-free (one 4B flag per block, one writer)
// — round 5 proved single-line atomicAdd compaction serializes (+2 us/step).
// Compute: round 3's validated segment dot (Q fragment in 64 regs/lane,
// u 16 B/lane, 30-shuffle fold + 16x17 pr matrix, Adam in registers).
// ---------------------------------------------------------------------------
__global__ __launch_bounds__(NTHR) void adam_persist(
        const float* __restrict__ Qs,
        float* u0, float* u1,
        const float* __restrict__ mean,
        float* __restrict__ w_out,
        int* __restrict__ flags) {
    __shared__ float pr[2][16][17];   // [buf][wave][local row], +1 pad

    const int tid  = threadIdx.x;
    const int bid  = blockIdx.x;
    const int wave = tid >> 6;
    const int lane = tid & 63;
    const int row  = bid * 16 + wave;
    const int col0 = wave * 256 + lane * 4;    // this lane's 4-element segment

    // ---- one-time: Q fragment -> registers (64 regs/lane) ----
    float4 qreg[16];
#pragma unroll
    for (int r = 0; r < 16; ++r)
        qreg[r] = *(const float4*)(Qs + (size_t)(bid * 16 + r) * MDIM + col0);

    float m = 0.0f, v = 0.0f, b1p = 1.0f, b2p = 1.0f;
    const float mrow = mean[row];
    float ucur = 1.0f - mrow;                  // u[row] lives in registers

    for (int t = 1; t <= NSTEPS; ++t) {
        const float* uin = (t & 1) ? u0 : u1;  // t=1 reads u0
        float*      uout = (t & 1) ? u1 : u0;  // u_t lands in buffer t&1
        const int b = t & 1;

        // ---- flat flag barrier: wave 0 sweeps all 256 step-(t-1) flags ----
        // flags[t-1] all set => every block drained its u_{t-1} stores (B2
        // idiom: s_waitcnt vmcnt(0) before s_barrier) AND finished reading
        // u_{t-2} (data dependence) -> RAW and WAR both safe.
        if (tid < 64) {
            const u64* f64 = (const u64*)(flags + (size_t)(t - 1) * NBLK);
            const u64 PAIR = 0x0000000100000001ULL;
            int spin = 0;
            for (;;) {
                u64 a = __hip_atomic_load(f64 + lane,      __ATOMIC_RELAXED, __HIP_MEMORY_SCOPE_AGENT);
                u64 c = __hip_atomic_load(f64 + lane + 64, __ATOMIC_RELAXED, __HIP_MEMORY_SCOPE_AGENT);
                if (__all((a == PAIR) & (c == PAIR))) break;
                if (++spin > (1 << 24)) break;   // fail visibly, never hang
            }
        }
        __syncthreads();               // B_go: u_{t-1} ready for all lanes

        // ---- load u segment (2x8B agent atomics bypass stale L2) ----
        u64 d0 = __hip_atomic_load((const u64*)(uin + col0),     __ATOMIC_RELAXED, __HIP_MEMORY_SCOPE_AGENT);
        u64 d1 = __hip_atomic_load((const u64*)(uin + col0 + 2), __ATOMIC_RELAXED, __HIP_MEMORY_SCOPE_AGENT);
        const float uv0 = __uint_as_float((unsigned)d0);
        const float uv1 = __uint_as_float((unsigned)(d0 >> 32));
        const float uv2 = __uint_as_float((unsigned)d1);
        const float uv3 = __uint_as_float((unsigned)(d1 >> 32));

        // ---- 16 row-partials over this lane's 4 columns ----
        float acc[16];
#pragma unroll
        for (int r = 0; r < 16; ++r) {
            float4 q = qreg[r];
            acc[r] = q.x * uv0 + q.y * uv1 + q.z * uv2 + q.w * uv3;
        }

        // ---- fold 16 values x 64 lanes -> 1 value/lane (30 shuffles) ----
#pragma unroll
        for (int stage = 0; stage < 4; ++stage) {
            const int mask = 32 >> stage;
            const int half = 8 >> stage;
            const bool hi = (lane & mask) != 0;
#pragma unroll
            for (int i = 0; i < half; ++i) {
                float plo = __shfl_xor(acc[i],        mask);
                float phi = __shfl_xor(acc[i + half], mask);
                acc[i] = hi ? (acc[i + half] + phi) : (acc[i] + plo);
            }
        }
        float acc0 = acc[0];
        acc0 += __shfl_xor(acc0, 1);   // finish sum within the quad
        acc0 += __shfl_xor(acc0, 2);

        if ((lane & 3) == 0) pr[b][wave][lane >> 2] = acc0;
        __syncthreads();               // B1: pr matrix ready

        // ---- cross-wave fold: wave w reduces local row w; Adam in regs ----
        float unew = ucur;
        if (lane < 16) {
            float p = pr[b][lane][wave];
            p += __shfl_xor(p, 1);
            p += __shfl_xor(p, 2);
            p += __shfl_xor(p, 4);
            p += __shfl_xor(p, 8);
            const float g = p;

            b1p *= B1C;
            b2p *= B2C;
            m = B1C * m + (1.0f - B1C) * g;
            v = B2C * v + (1.0f - B2C) * g * g;
            const float denom = sqrtf(v) / sqrtf(1.0f - b2p) + EPSC;
            unew = ucur - (0.1f / (1.0f - b1p)) * m / denom;
            ucur = unew;
        }

        if (t < NSTEPS) {              // nobody consumes u_199 from memory
            if (lane == 0)
                __hip_atomic_store(uout + row, unew, __ATOMIC_RELAXED,
                                   __HIP_MEMORY_SCOPE_AGENT);
            // B2: each wave's s_waitcnt vmcnt(0) before s_barrier drains its
            // u store -> after the barrier ALL 16 rows are agent-visible.
            __syncthreads();

            if (tid == 0)
                __hip_atomic_store(flags + (size_t)t * NBLK + bid, 1,
                                   __ATOMIC_RELAXED, __HIP_MEMORY_SCOPE_AGENT);
        }
    }

    if (lane == 0) w_out[row] = ucur + mrow;
}

extern "C" void kernel_launch(void* const* d_in, const int* in_sizes, int n_in,
                              void* d_out, int out_size, void* d_ws, size_t ws_size,
                              hipStream_t stream) {
    const float* mean = (const float*)d_in[0];   // (4096,)
    const float* va   = (const float*)d_in[1];   // (4096,4096)
    float* w_out = (float*)d_out;                // (4096,)

    float* ws = (float*)d_ws;
    float* Qs  = ws;                              // 64 MB
    float* u0  = ws + (size_t)MDIM * MDIM;        // 16 KB
    float* u1  = u0 + MDIM;                       // 16 KB
    int*   flg = (int*)(u1 + MDIM);               // (NSTEPS+1)*256 ints

    const int nflags = (NSTEPS + 1) * NBLK;

    prep_qs<<<dim3(MDIM / 32, MDIM / 32), dim3(32, 8), 0, stream>>>(va, Qs);
    init_state<<<(nflags + 255) / 256, 256, 0, stream>>>(mean, u0, flg, nflags);

    void* args[] = { (void*)&Qs, (void*)&u0, (void*)&u1,
                     (void*)&mean, (void*)&w_out, (void*)&flg };
    hipLaunchCooperativeKernel((const void*)adam_persist,
                               dim3(NBLK), dim3(NTHR), args, 0, stream);
}